// Round 1
// baseline (207.900 us; speedup 1.0000x reference)
//
#include <hip/hip_runtime.h>
#include <cstdint>
#include <cstddef>

// Exact 3-level radix select (11/10/11 bits) on order-transformed x bits among
// t<0 entries (t = -1 exactly => negative_loss = softplus(x), strictly
// increasing in x).
//
// R5 changes vs the 177 µs kernel (traffic: 304 MB -> 211 MB/iter):
//  * k1 compacts transformed u-values of negatives into per-wave private
//    segments (13.7 MB, zero-contention: register cursor + __shfl prefix scan)
//    -> levels 2/3 read 13.7 MB instead of re-reading x,t (82 MB).
//  * 2^21-bin global histogram (8 MB + memset + 8 MB scan) replaced by
//    tiny level-2 (1024 bins, bits[20:11]) and level-3 (2048 bins, bits[10:0])
//    global histograms; only ~75k / ~75 atomic increments, spread over bins.
//  * k1 emits a 2-bit class map (pos/neg/ignore, 2.56 MB); k_final reads
//    x + classmap instead of x + t (-38 MB).
// Final pass: fast __expf/__logf values, exact bit-compare mask, precise
// log1pf re-check only within a 256-ulp guard band at the boundary (unchanged).
//
// ws layout (assumes ws_size >= ~48 MB; observed harness ws = 256 MiB):
//   [0     ..  8192)   hist1  (2048 u32)  bits [31:21]
//   [8192  .. 12288)   hist2  (1024 u32)  bits [20:11]
//   [12288 .. 20480)   hist3  (2048 u32)  bits [10:0]
//   [20480 .. 20544)   SelState
//   [24576 .. 40960)   wvcnt  (<=4096 u32, per-wave segment counts)
//   [40960 .. +n/4)    cmap   (2-bit class per element, byte per quad)
//   [align256 ..)      cand1  (nseg * segw u32 segments)

struct SelState {
    uint32_t prefix1;  // 11-bit level-1 prefix
    uint32_t k1rem;    // remaining rank within level-1 bin
    uint32_t prefix2;  // 10-bit level-2 prefix
    uint32_t k2rem;    // remaining rank within level-2 bin
    uint32_t u_kth;    // final: transformed bits of k-th largest x
    float    thr_nl;   // final: precise loss-space threshold
    uint32_t done;
};

#define GUARD 256u

__device__ __forceinline__ uint32_t xform(uint32_t b) {
    return ((int32_t)b < 0) ? ~b : (b | 0x80000000u);
}
__device__ __forceinline__ float unxform(uint32_t u) {
    uint32_t b = (u & 0x80000000u) ? (u ^ 0x80000000u) : ~u;
    return __uint_as_float(b);
}
// precise chain — matches reference fp32 semantics; used only for the
// threshold value and the rare guard-band compare.
__device__ __forceinline__ float neg_loss_precise(float x, float t) {
#pragma clang fp contract(off)
    return (fmaxf(-x, 0.0f) - x * t) + log1pf(expf(-fabsf(x)));
}

// wave-wide inclusive scan -> exclusive offset + total (64 lanes)
__device__ __forceinline__ void wscan(uint32_t m, int lane, uint32_t& excl, uint32_t& tot) {
    uint32_t inc = m;
#pragma unroll
    for (int d = 1; d < 64; d <<= 1) {
        uint32_t v = __shfl_up(inc, (unsigned)d, 64);
        if (lane >= d) inc += v;
    }
    excl = inc - m;
    tot = __shfl(inc, 63, 64);
}

// per-quad: u values (0 if not negative), class byte, LDS histogram
__device__ __forceinline__ uint32_t quad_u_cls(uint32_t* my, float4 xv, float4 tv,
        uint32_t& u0, uint32_t& u1, uint32_t& u2, uint32_t& u3) {
    u0 = (tv.x < 0.0f) ? xform(__float_as_uint(xv.x)) : 0u;
    u1 = (tv.y < 0.0f) ? xform(__float_as_uint(xv.y)) : 0u;
    u2 = (tv.z < 0.0f) ? xform(__float_as_uint(xv.z)) : 0u;
    u3 = (tv.w < 0.0f) ? xform(__float_as_uint(xv.w)) : 0u;
    uint32_t cls = ((tv.x > 0.0f) ? 1u : ((tv.x < 0.0f) ? 2u : 0u))
                 | (((tv.y > 0.0f) ? 1u : ((tv.y < 0.0f) ? 2u : 0u)) << 2)
                 | (((tv.z > 0.0f) ? 1u : ((tv.z < 0.0f) ? 2u : 0u)) << 4)
                 | (((tv.w > 0.0f) ? 1u : ((tv.w < 0.0f) ? 2u : 0u)) << 6);
    if (u0) atomicAdd(&my[u0 >> 21], 1u);
    if (u1) atomicAdd(&my[u1 >> 21], 1u);
    if (u2) atomicAdd(&my[u2 >> 21], 1u);
    if (u3) atomicAdd(&my[u3 >> 21], 1u);
    return cls;
}

// ---------- k1: 11-bit LDS histogram + negative compaction + class map ----------
__global__ __launch_bounds__(256) void k1_hist(
        const float* __restrict__ x, const float* __restrict__ t,
        uint32_t* __restrict__ hist1, uint32_t* __restrict__ cand1,
        uint32_t* __restrict__ wvcnt, uint8_t* __restrict__ cmap,
        int n, int segw) {
    __shared__ uint32_t lh[2 * 2049];   // 2-way replicated (+1 pad)
    for (int j = threadIdx.x; j < 2 * 2049; j += 256) lh[j] = 0;
    __syncthreads();
    uint32_t* my = &lh[(threadIdx.x & 1) * 2049];

    const float4* x4 = (const float4*)x;
    const float4* t4 = (const float4*)t;
    const int n4 = n >> 2;
    const int S = gridDim.x * 256;
    const int lane = threadIdx.x & 63;
    const int wid  = threadIdx.x >> 6;
    uint32_t* wseg = cand1 + (size_t)(blockIdx.x * 4 + wid) * (size_t)segw;
    uint32_t wcur = 0;   // wave-uniform segment cursor (no atomics)

    // block-uniform count of full 4x-unrolled batches (avoids wave divergence,
    // required because appends use wave-wide shfl scans)
    int M4 = 0;
    {
        long rem = (long)n4 - 1 - (long)(blockIdx.x * 256 + 255);
        if (rem >= 0) {
            long T = rem / S;
            if (T >= 3) M4 = (int)((T - 3) / 4 + 1);
        }
    }
    int i = blockIdx.x * 256 + threadIdx.x;

    for (int b = 0; b < M4; ++b, i += 4 * S) {   // 8 independent 16B loads in flight
        float4 xa = x4[i], xb = x4[i + S], xc = x4[i + 2 * S], xd = x4[i + 3 * S];
        float4 ta = t4[i], tb = t4[i + S], tc = t4[i + 2 * S], td = t4[i + 3 * S];
        uint32_t u0, u1, u2, u3, u4_, u5, u6, u7, u8, u9, uA, uB, uC, uD, uE, uF;
        uint32_t ca = quad_u_cls(my, xa, ta, u0, u1, u2, u3);
        uint32_t cb = quad_u_cls(my, xb, tb, u4_, u5, u6, u7);
        uint32_t cc = quad_u_cls(my, xc, tc, u8, u9, uA, uB);
        uint32_t cd = quad_u_cls(my, xd, td, uC, uD, uE, uF);
        cmap[i]         = (uint8_t)ca;
        cmap[i + S]     = (uint8_t)cb;
        cmap[i + 2 * S] = (uint8_t)cc;
        cmap[i + 3 * S] = (uint8_t)cd;
        uint32_t m = (u0 != 0) + (u1 != 0) + (u2 != 0) + (u3 != 0)
                   + (u4_ != 0) + (u5 != 0) + (u6 != 0) + (u7 != 0)
                   + (u8 != 0) + (u9 != 0) + (uA != 0) + (uB != 0)
                   + (uC != 0) + (uD != 0) + (uE != 0) + (uF != 0);
        uint32_t excl, tot;
        wscan(m, lane, excl, tot);
        uint32_t p = wcur + excl;
        if (u0)  wseg[p++] = u0;
        if (u1)  wseg[p++] = u1;
        if (u2)  wseg[p++] = u2;
        if (u3)  wseg[p++] = u3;
        if (u4_) wseg[p++] = u4_;
        if (u5)  wseg[p++] = u5;
        if (u6)  wseg[p++] = u6;
        if (u7)  wseg[p++] = u7;
        if (u8)  wseg[p++] = u8;
        if (u9)  wseg[p++] = u9;
        if (uA)  wseg[p++] = uA;
        if (uB)  wseg[p++] = uB;
        if (uC)  wseg[p++] = uC;
        if (uD)  wseg[p++] = uD;
        if (uE)  wseg[p++] = uE;
        if (uF)  wseg[p++] = uF;
        wcur += tot;
    }

    // masked single-quad remainder (wave-uniform loop via __any)
    for (; __any(i < n4); i += S) {
        const bool act = i < n4;
        float4 xa = act ? x4[i] : make_float4(0.f, 0.f, 0.f, 0.f);
        float4 ta = act ? t4[i] : make_float4(0.f, 0.f, 0.f, 0.f);
        uint32_t u0, u1, u2, u3;
        uint32_t ca = quad_u_cls(my, xa, ta, u0, u1, u2, u3);
        if (act) cmap[i] = (uint8_t)ca;
        uint32_t m = (u0 != 0) + (u1 != 0) + (u2 != 0) + (u3 != 0);
        uint32_t excl, tot;
        wscan(m, lane, excl, tot);
        uint32_t p = wcur + excl;
        if (u0) wseg[p++] = u0;
        if (u1) wseg[p++] = u1;
        if (u2) wseg[p++] = u2;
        if (u3) wseg[p++] = u3;
        wcur += tot;
    }

    // n % 4 tail (block 0 only; <4 elems; single masked shot; no cmap —
    // k_final reads t directly for the tail)
    if (blockIdx.x == 0) {
        int j = (n4 << 2) + threadIdx.x;
        const bool act = j < n;
        float xx = act ? x[j] : 0.0f;
        float tt = act ? t[j] : 0.0f;
        uint32_t u0 = (tt < 0.0f) ? xform(__float_as_uint(xx)) : 0u;
        if (u0) atomicAdd(&my[u0 >> 21], 1u);
        uint32_t excl, tot;
        wscan(u0 != 0 ? 1u : 0u, lane, excl, tot);
        if (u0) wseg[wcur + excl] = u0;
        wcur += tot;
    }

    if (lane == 0) wvcnt[blockIdx.x * 4 + wid] = wcur;

    __syncthreads();
    for (int b2 = threadIdx.x; b2 < 2048; b2 += 256) {
        uint32_t c = lh[b2] + lh[2049 + b2];
        if (c) atomicAdd(&hist1[b2], c);
    }
}

// ---------------- s1: 1 block, pick 11-bit prefix ----------------
__global__ __launch_bounds__(256) void s1_scan(
        const uint32_t* __restrict__ hist1, SelState* __restrict__ st,
        const int* __restrict__ kptr) {
    __shared__ uint32_t part[256];
    const int tid = threadIdx.x;
    uint32_t cnt[8];
    uint32_t lsum = 0;
#pragma unroll
    for (int j = 0; j < 8; ++j) { cnt[j] = hist1[tid * 8 + j]; lsum += cnt[j]; }
    part[tid] = lsum;
    __syncthreads();
    for (int off = 1; off < 256; off <<= 1) {   // inclusive suffix sum
        uint32_t add = (tid + off < 256) ? part[tid + off] : 0u;
        __syncthreads();
        part[tid] += add;
        __syncthreads();
    }
    const uint32_t total = part[0];
    int kk = *kptr;
    uint32_t k = (kk > 0) ? (uint32_t)kk : 0u;
    if (k == 0u) {   // keep all negatives
        if (tid == 0) { st->u_kth = 0xFFFFFFFFu; st->thr_nl = __int_as_float(0x7F800000); st->done = 1u; }
        return;
    }
    if (k > total) { // drop all negatives
        if (tid == 0) { st->u_kth = 0u; st->thr_nl = 0.0f; st->done = 1u; }
        return;
    }
    uint32_t A = (tid < 255) ? part[tid + 1] : 0u;  // strictly-above count
#pragma unroll
    for (int j = 7; j >= 0; --j) {
        uint32_t c = cnt[j];
        if (A < k && k <= A + c) {   // exactly one (thread,bin)
            st->prefix1 = (uint32_t)(tid * 8 + j);
            st->k1rem = k - A;       // done stays 0 (memset)
        }
        A += c;
    }
}

// ---------- k2: level-2 histogram (bits 20:11) over compacted candidates ----------
__global__ __launch_bounds__(256) void k2_hist2(
        const uint32_t* __restrict__ cand1, const uint32_t* __restrict__ wvcnt,
        uint32_t* __restrict__ hist2, const SelState* __restrict__ st,
        int nseg, int segw) {
    __shared__ uint32_t s_pref, s_done;
    if (threadIdx.x == 0) { s_pref = st->prefix1; s_done = st->done; }
    __syncthreads();
    if (s_done) return;
    const uint32_t pref = s_pref;
    for (int s = blockIdx.x; s < nseg; s += gridDim.x) {
        const uint32_t cnt = wvcnt[s];
        const uint32_t* base = cand1 + (size_t)s * (size_t)segw;
        const uint4* b4 = (const uint4*)base;
        const uint32_t c4 = cnt >> 2;
        for (uint32_t j = threadIdx.x; j < c4; j += 256) {
            uint4 v = b4[j];
            if ((v.x >> 21) == pref) atomicAdd(&hist2[(v.x >> 11) & 1023u], 1u);
            if ((v.y >> 21) == pref) atomicAdd(&hist2[(v.y >> 11) & 1023u], 1u);
            if ((v.z >> 21) == pref) atomicAdd(&hist2[(v.z >> 11) & 1023u], 1u);
            if ((v.w >> 21) == pref) atomicAdd(&hist2[(v.w >> 11) & 1023u], 1u);
        }
        if (threadIdx.x < (cnt & 3u)) {
            uint32_t u = base[(c4 << 2) + threadIdx.x];
            if ((u >> 21) == pref) atomicAdd(&hist2[(u >> 11) & 1023u], 1u);
        }
    }
}

// ---------------- s2: 1 block, pick 10-bit level-2 prefix ----------------
__global__ __launch_bounds__(256) void s2_scan(
        const uint32_t* __restrict__ hist2, SelState* __restrict__ st) {
    if (st->done) return;   // uniform
    __shared__ uint32_t part[256];
    const int tid = threadIdx.x;
    uint32_t cnt[4];
    uint32_t lsum = 0;
#pragma unroll
    for (int j = 0; j < 4; ++j) { cnt[j] = hist2[tid * 4 + j]; lsum += cnt[j]; }
    part[tid] = lsum;
    __syncthreads();
    for (int off = 1; off < 256; off <<= 1) {
        uint32_t add = (tid + off < 256) ? part[tid + off] : 0u;
        __syncthreads();
        part[tid] += add;
        __syncthreads();
    }
    const uint32_t k = st->k1rem;
    uint32_t A = (tid < 255) ? part[tid + 1] : 0u;
#pragma unroll
    for (int j = 3; j >= 0; --j) {
        uint32_t c = cnt[j];
        if (A < k && k <= A + c) {
            st->prefix2 = (uint32_t)(tid * 4 + j);
            st->k2rem = k - A;
        }
        A += c;
    }
}

// ---------- k3: level-3 histogram (bits 10:0) over compacted candidates ----------
__global__ __launch_bounds__(256) void k3_hist3(
        const uint32_t* __restrict__ cand1, const uint32_t* __restrict__ wvcnt,
        uint32_t* __restrict__ hist3, const SelState* __restrict__ st,
        int nseg, int segw) {
    __shared__ uint32_t s_pref21, s_done;
    if (threadIdx.x == 0) {
        s_pref21 = (st->prefix1 << 10) | st->prefix2;
        s_done = st->done;
    }
    __syncthreads();
    if (s_done) return;
    const uint32_t pref21 = s_pref21;
    for (int s = blockIdx.x; s < nseg; s += gridDim.x) {
        const uint32_t cnt = wvcnt[s];
        const uint32_t* base = cand1 + (size_t)s * (size_t)segw;
        const uint4* b4 = (const uint4*)base;
        const uint32_t c4 = cnt >> 2;
        for (uint32_t j = threadIdx.x; j < c4; j += 256) {
            uint4 v = b4[j];
            if ((v.x >> 11) == pref21) atomicAdd(&hist3[v.x & 0x7FFu], 1u);
            if ((v.y >> 11) == pref21) atomicAdd(&hist3[v.y & 0x7FFu], 1u);
            if ((v.z >> 11) == pref21) atomicAdd(&hist3[v.z & 0x7FFu], 1u);
            if ((v.w >> 11) == pref21) atomicAdd(&hist3[v.w & 0x7FFu], 1u);
        }
        if (threadIdx.x < (cnt & 3u)) {
            uint32_t u = base[(c4 << 2) + threadIdx.x];
            if ((u >> 11) == pref21) atomicAdd(&hist3[u & 0x7FFu], 1u);
        }
    }
}

// ---------------- s3: 1 block, pick final 11 bits -> u_kth ----------------
__global__ __launch_bounds__(256) void s3_scan(
        const uint32_t* __restrict__ hist3, SelState* __restrict__ st) {
    if (st->done) return;   // uniform
    __shared__ uint32_t part[256];
    const int tid = threadIdx.x;
    uint32_t cnt[8];
    uint32_t lsum = 0;
#pragma unroll
    for (int j = 0; j < 8; ++j) { cnt[j] = hist3[tid * 8 + j]; lsum += cnt[j]; }
    part[tid] = lsum;
    __syncthreads();
    for (int off = 1; off < 256; off <<= 1) {
        uint32_t add = (tid + off < 256) ? part[tid + off] : 0u;
        __syncthreads();
        part[tid] += add;
        __syncthreads();
    }
    const uint32_t k = st->k2rem;
    uint32_t A = (tid < 255) ? part[tid + 1] : 0u;
#pragma unroll
    for (int j = 7; j >= 0; --j) {
        uint32_t c = cnt[j];
        if (A < k && k <= A + c) {
            uint32_t u = (st->prefix1 << 21) | (st->prefix2 << 11) | (uint32_t)(tid * 8 + j);
            st->u_kth = u;
            st->thr_nl = neg_loss_precise(unxform(u), -1.0f);  // t = -1 exactly
            st->done = 1u;
        }
        A += c;
    }
}

// ---------------- final: fast-math values, bit-exact mask, class map ----------------
__device__ __forceinline__ float fin1c(float xx, uint32_t cls, uint32_t ukth, float thr) {
    float lp = __logf(1.0f + __expf(-fabsf(xx)));   // HW exp/log
    float v = 0.0f;
    if (cls == 1u) {                    // t = +1: same arithmetic as x*t path
        v = (fmaxf(xx, 0.0f) - xx) + lp;
    } else if (cls == 2u) {             // t = -1
        uint32_t u = xform(__float_as_uint(xx));
        bool keep = u < ukth;
        if (keep && (ukth - u) < GUARD)             // ~0 lanes hit this
            keep = neg_loss_precise(xx, -1.0f) < thr;
        if (keep) v = (fmaxf(-xx, 0.0f) + xx) + lp;
    }
    return v;
}

__device__ __forceinline__ float4 fin_quadc(float4 xv, uint32_t cb, uint32_t ukth, float thr) {
    float4 r;
    r.x = fin1c(xv.x, cb & 3u, ukth, thr);
    r.y = fin1c(xv.y, (cb >> 2) & 3u, ukth, thr);
    r.z = fin1c(xv.z, (cb >> 4) & 3u, ukth, thr);
    r.w = fin1c(xv.w, (cb >> 6) & 3u, ukth, thr);
    return r;
}

// tail helper: original t-based path
__device__ __forceinline__ float fin1t(float xx, float tt, uint32_t ukth, float thr) {
    float lp = __logf(1.0f + __expf(-fabsf(xx)));
    float v = 0.0f;
    if (tt > 0.0f) {
        v = fmaxf(xx, 0.0f) - xx * tt + lp;
    } else if (tt < 0.0f) {
        uint32_t u = xform(__float_as_uint(xx));
        bool keep = u < ukth;
        if (keep && (ukth - u) < GUARD)
            keep = neg_loss_precise(xx, tt) < thr;
        if (keep) v = fmaxf(-xx, 0.0f) - xx * tt + lp;
    }
    return v;
}

__global__ __launch_bounds__(256) void k_final(
        const float* __restrict__ x, const float* __restrict__ t,
        const uint8_t* __restrict__ cmap, const SelState* __restrict__ st,
        float* __restrict__ out, int n) {
    const uint32_t ukth = st->u_kth;
    const float thr = st->thr_nl;
    const float4* x4 = (const float4*)x;
    float4* o4 = (float4*)out;
    const int n4 = n >> 2;
    const int S = gridDim.x * 256;
    int i = blockIdx.x * 256 + threadIdx.x;
    for (; i + 3 * S < n4; i += 4 * S) {
        float4 xa = x4[i], xb = x4[i + S], xc = x4[i + 2 * S], xd = x4[i + 3 * S];
        uint32_t ca = cmap[i], cb = cmap[i + S], cc = cmap[i + 2 * S], cd = cmap[i + 3 * S];
        o4[i]         = fin_quadc(xa, ca, ukth, thr);
        o4[i + S]     = fin_quadc(xb, cb, ukth, thr);
        o4[i + 2 * S] = fin_quadc(xc, cc, ukth, thr);
        o4[i + 3 * S] = fin_quadc(xd, cd, ukth, thr);
    }
    for (; i < n4; i += S) {
        float4 xa = x4[i];
        uint32_t ca = cmap[i];
        o4[i] = fin_quadc(xa, ca, ukth, thr);
    }
    if (blockIdx.x == 0) {  // n % 4 tail: no cmap — use t directly
        for (int j = (n4 << 2) + threadIdx.x; j < n; j += 256) {
            out[j] = fin1t(x[j], t[j], ukth, thr);
        }
    }
}

extern "C" void kernel_launch(void* const* d_in, const int* in_sizes, int n_in,
                              void* d_out, int out_size, void* d_ws, size_t ws_size,
                              hipStream_t stream) {
    const float* x = (const float*)d_in[0];
    const float* t = (const float*)d_in[1];
    const int* kptr = (const int*)d_in[2];
    float* out = (float*)d_out;
    const int n = in_sizes[0];
    if (n <= 0) return;

    const int n4 = n >> 2;
    int work = (n4 + 255) / 256;
    if (work < 1) work = 1;
    int grid = work < 1024 ? work : 1024;   // 4 blocks/CU; x4 unroll covers depth
    const int S = grid * 256;
    const int Q = (n4 + S - 1) / S;          // max quads per thread
    const int segw = 256 * Q + 4;            // words per wave segment (16B-aligned)
    const int nseg = grid * 4;

    char* ws = (char*)d_ws;
    uint32_t* hist1 = (uint32_t*)(ws + 0);          // 2048 u32
    uint32_t* hist2 = (uint32_t*)(ws + 8192);       // 1024 u32
    uint32_t* hist3 = (uint32_t*)(ws + 12288);      // 2048 u32
    SelState* st    = (SelState*)(ws + 20480);
    uint32_t* wvcnt = (uint32_t*)(ws + 24576);      // nseg <= 4096 u32 (no memset: always written)
    uint8_t*  cmap  = (uint8_t*)(ws + 40960);       // n4 bytes
    size_t c1off = (40960 + (size_t)n4 + 255) & ~(size_t)255;
    uint32_t* cand1 = (uint32_t*)(ws + c1off);      // nseg*segw u32 (~42 MB @ n=10.24M)

    // zero hists + state only (~20 KB vs previous 8.4 MB)
    hipMemsetAsync(d_ws, 0, 20544, stream);

    k1_hist <<<grid, 256, 0, stream>>>(x, t, hist1, cand1, wvcnt, cmap, n, segw);
    s1_scan <<<1, 256, 0, stream>>>(hist1, st, kptr);
    k2_hist2<<<grid, 256, 0, stream>>>(cand1, wvcnt, hist2, st, nseg, segw);
    s2_scan <<<1, 256, 0, stream>>>(hist2, st);
    k3_hist3<<<grid, 256, 0, stream>>>(cand1, wvcnt, hist3, st, nseg, segw);
    s3_scan <<<1, 256, 0, stream>>>(hist3, st);
    k_final <<<grid, 256, 0, stream>>>(x, t, cmap, st, out, n);
}